// Round 2
// baseline (467.967 us; speedup 1.0000x reference)
//
#include <hip/hip_runtime.h>
#include <hip/hip_bf16.h>
#include <math.h>

// MultiEmbodimentActionEncoder: B=64,T=64,A=64,H=1024,C=16
// R2: cat-sorted paired batches per block (M=128), n-strip=64 (16 cols/wave),
// grid (16 strips x 32 pair-entries). Same-cat pair shares one B-fragment
// stream -> B-load:MFMA ratio 1:1, and same-XCD L2 reuse of weight chunks.

typedef short bf16x8 __attribute__((ext_vector_type(8)));
typedef float floatx4 __attribute__((ext_vector_type(4)));

__device__ inline short f2bf(float f) {
  union { float f; unsigned u; } v; v.f = f;
  unsigned u = v.u;
  unsigned r = (u + 0x7fffu + ((u >> 16) & 1u)) >> 16;   // RTNE
  return (short)(r & 0xffffu);
}

__device__ inline bf16x8 loadB(const float* __restrict__ wp) {
  constexpr int N = 1024;
  bf16x8 t;
  #pragma unroll
  for (int j = 0; j < 8; ++j) t[j] = f2bf(wp[(size_t)j * N]);
  return t;
}

// Block: 256 threads = 4 waves. Wave w owns 16 cols (nt=1); mt=8 m-tiles
// (rows 0-63 -> batch b0, 64-127 -> batch b1). B-frag: lane holds
// W[k=quad*8+j][n=l16] (8 strided fp32 -> bf16). A-frag: contiguous 16B.
template<int K, bool A_F32, bool SWISH, bool OUT_BF16>
__global__ __launch_bounds__(256) void gemm_kernel(
    const void* __restrict__ Aall, int lda,
    const float* __restrict__ Wall,   // (16, K, 1024)
    const float* __restrict__ bias,   // (16, 1024)
    const int* __restrict__ cat_ids,
    void* __restrict__ Out, int ldo)
{
  constexpr int N = 1024;
  __shared__ int s_b[64], s_c[64];

  const int tid = threadIdx.x;
  // wave 0: stable counting sort of the 64 cat_ids via ballots (~300 cyc)
  if (tid < 64) {
    const int myc = cat_ids[tid];
    int pos = 0;
    #pragma unroll
    for (int c = 0; c < 16; ++c) {
      unsigned long long m = __ballot(myc == c);
      if (c < myc)       pos += __popcll(m);
      else if (c == myc) pos += __popcll(m & ((1ull << tid) - 1ull));
    }
    s_b[pos] = tid;
    s_c[pos] = myc;
  }
  __syncthreads();

  const int e  = blockIdx.y;                 // pair entry 0..31
  const int b0 = s_b[2 * e],     b1 = s_b[2 * e + 1];
  const int c0 = s_c[2 * e],     c1 = s_c[2 * e + 1];
  const bool same = (c0 == c1);

  const int wave = tid >> 6;
  const int lane = tid & 63;
  const int quad = lane >> 4;
  const int l16  = lane & 15;
  const int n    = blockIdx.x * 64 + wave * 16 + l16;

  const float* W0 = Wall + (size_t)c0 * K * N;
  const float* W1 = Wall + (size_t)c1 * K * N;

  // per-lane A row base pointers (8 m-tiles)
  const char* arow[8];
  #pragma unroll
  for (int mt = 0; mt < 8; ++mt) {
    const int row = ((mt < 4) ? b0 : b1) * 64 + (mt & 3) * 16 + l16;
    arow[mt] = (const char*)Aall + (size_t)row * lda * (A_F32 ? 4 : 2);
  }

  floatx4 acc[8];
  #pragma unroll
  for (int mt = 0; mt < 8; ++mt) acc[mt] = (floatx4){0.f, 0.f, 0.f, 0.f};

  #pragma unroll 2
  for (int k0 = 0; k0 < K; k0 += 32) {
    const int kk = k0 + quad * 8;

    bf16x8 bf0 = loadB(W0 + (size_t)kk * N + n);
    bf16x8 bf1;
    if (same) bf1 = bf0;                       // block-uniform branch
    else      bf1 = loadB(W1 + (size_t)kk * N + n);

    bf16x8 af[8];
    #pragma unroll
    for (int mt = 0; mt < 8; ++mt) {
      if constexpr (A_F32) {
        const floatx4* p = (const floatx4*)(arow[mt] + (size_t)kk * 4);
        floatx4 x0 = p[0], x1 = p[1];
        bf16x8 t;
        t[0] = f2bf(x0[0]); t[1] = f2bf(x0[1]); t[2] = f2bf(x0[2]); t[3] = f2bf(x0[3]);
        t[4] = f2bf(x1[0]); t[5] = f2bf(x1[1]); t[6] = f2bf(x1[2]); t[7] = f2bf(x1[3]);
        af[mt] = t;
      } else {
        af[mt] = *(const bf16x8*)(arow[mt] + (size_t)kk * 2);
      }
    }

    #pragma unroll
    for (int mt = 0; mt < 8; ++mt)
      acc[mt] = __builtin_amdgcn_mfma_f32_16x16x32_bf16(
          af[mt], (mt < 4) ? bf0 : bf1, acc[mt], 0, 0, 0);
  }

  // Epilogue. C/D layout: row = quad*4 + r, col = l16.
  const float bv0 = bias[(size_t)c0 * N + n];
  const float bv1 = bias[(size_t)c1 * N + n];
  #pragma unroll
  for (int mt = 0; mt < 8; ++mt) {
    const int bb = (mt < 4) ? b0 : b1;
    const float bv = (mt < 4) ? bv0 : bv1;
    #pragma unroll
    for (int r = 0; r < 4; ++r) {
      const int row = bb * 64 + (mt & 3) * 16 + quad * 4 + r;
      float v = acc[mt][r] + bv;
      if constexpr (SWISH) v = v / (1.f + __expf(-v));
      if constexpr (OUT_BF16)
        ((short*)Out)[(size_t)row * ldo + n] = f2bf(v);
      else
        ((float*)Out)[(size_t)row * ldo + n] = v;
    }
  }
}

// tau: per batch one 1024-vector (timestep constant across T), broadcast to
// 64 rows of x's right half (row stride 2048 bf16).
__global__ __launch_bounds__(256) void tau_kernel(const int* __restrict__ ts,
                                                  short* __restrict__ x)
{
  const int b = blockIdx.x;
  const float t = (float)ts[b];
  const int tid = threadIdx.x;
  #pragma unroll
  for (int q = 0; q < 4; ++q) {
    const int i  = q * 256 + tid;          // [0,1024)
    const int hi = i & 511;
    const float e = __expf(-(float)hi * 0.017988946039015980f);  // ln(1e4)/512
    const float freq = t * e;
    const float v = (i < 512) ? sinf(freq) : cosf(freq);
    const short sv = f2bf(v);
    short* base = x + (size_t)(b * 64) * 2048 + 1024 + i;
    #pragma unroll 4
    for (int tt = 0; tt < 64; ++tt) base[(size_t)tt * 2048] = sv;
  }
}

extern "C" void kernel_launch(void* const* d_in, const int* in_sizes, int n_in,
                              void* d_out, int out_size, void* d_ws, size_t ws_size,
                              hipStream_t stream) {
  const float* actions   = (const float*)d_in[0];
  const int*   timesteps = (const int*)  d_in[1];
  const int*   cat_ids   = (const int*)  d_in[2];
  const float* W1 = (const float*)d_in[3];
  const float* b1 = (const float*)d_in[4];
  const float* W2 = (const float*)d_in[5];
  const float* b2 = (const float*)d_in[6];
  const float* W3 = (const float*)d_in[7];
  const float* b3 = (const float*)d_in[8];

  short* x = (short*)d_ws;                       // (4096, 2048) bf16 = 16 MiB
  short* h = x + (size_t)64 * 64 * 2048;         // (4096, 1024) bf16 =  8 MiB

  dim3 grid(16, 32), blk(256);

  // GEMM1: a_emb = actions @ W1[c] + b1[c] -> x[:, 0:1024]
  gemm_kernel<64, true, false, true><<<grid, blk, 0, stream>>>(
      (const void*)actions, 64, W1, b1, cat_ids, (void*)x, 2048);

  // tau -> x[:, 1024:2048]
  tau_kernel<<<64, 256, 0, stream>>>(timesteps, x);

  // GEMM2 + swish: h = swish(x @ W2[c] + b2[c])
  gemm_kernel<2048, false, true, true><<<grid, blk, 0, stream>>>(
      (const void*)x, 2048, W2, b2, cat_ids, (void*)h, 1024);

  // GEMM3: out = h @ W3[c] + b3[c]  (fp32)
  gemm_kernel<1024, false, false, false><<<grid, blk, 0, stream>>>(
      (const void*)h, 1024, W3, b3, cat_ids, d_out, 1024);
}

// Round 4
// 376.418 us; speedup vs baseline: 1.2432x; 1.2432x over previous
//
#include <hip/hip_runtime.h>
#include <hip/hip_bf16.h>
#include <math.h>

// MultiEmbodimentActionEncoder B=64,T=64,A=64,H=1024,C=16
// R4 (= R3 with compile fix): async global_load_lds double-buffered fp32
// W-tile staging, cat-sorted even-padded batch pairs (M=128), N=128/block,
// k-tile=32.

typedef short bf16x8 __attribute__((ext_vector_type(8)));
typedef float floatx4 __attribute__((ext_vector_type(4)));

__device__ inline short f2bf(float f) {
  union { float f; unsigned u; } v; v.f = f;
  unsigned u = v.u;
  return (short)(((u + 0x7fffu + ((u >> 16) & 1u)) >> 16) & 0xffffu);
}

// pack two fp32 -> two bf16 (RTNE) in one 32-bit word: lo=a, hi=b
__device__ inline unsigned pk2(float a, float b) {
  union { float f; unsigned u; } x, y; x.f = a; y.f = b;
  unsigned ua = (x.u + 0x7fffu + ((x.u >> 16) & 1u)) >> 16;
  unsigned ub = (y.u + 0x7fffu + ((y.u >> 16) & 1u)) >> 16;
  return (ua & 0xffffu) | (ub << 16);
}

#if __has_builtin(__builtin_amdgcn_global_load_lds)
__device__ inline void async16(float* lds, const float* g) {
  __builtin_amdgcn_global_load_lds(
      (const __attribute__((address_space(1))) unsigned int*)g,
      (__attribute__((address_space(3))) unsigned int*)lds, 16, 0, 0);
}
#define ASYNC_LDS 1
#else
__device__ inline void async16(float* lds, const float* g) {
  *(floatx4*)lds = *(const floatx4*)g;   // fallback: sync copy
}
#define ASYNC_LDS 0
#endif

// Stage 32(k) x 128(n) fp32 W tile into tilebuf with chunk swizzle:
// slot s (16B) holds W[k=s>>5][cols 4*cc..4*cc+3], cc = ((s&31) - 4*(k>>3))&31.
// Wsrc = W[c] + k0*1024 + ns ; row stride 1024 floats.
__device__ inline void stage_tile(float* tilebuf, const float* __restrict__ Wsrc,
                                  int tid) {
  const int wave = tid >> 6;
#if ASYNC_LDS
  #pragma unroll
  for (int i = 0; i < 4; ++i) {
    const int s  = i * 256 + tid;
    const int k  = s >> 5;
    const int p  = s & 31;
    const int cc = (p - 4 * (k >> 3)) & 31;
    const float* g = Wsrc + (size_t)k * 1024 + cc * 4;
    float* l = tilebuf + (size_t)(i * 256 + wave * 64) * 4;  // wave-uniform base
    async16(l, g);
  }
#else
  #pragma unroll
  for (int i = 0; i < 4; ++i) {
    const int s  = i * 256 + tid;
    const int k  = s >> 5;
    const int p  = s & 31;
    const int cc = (p - 4 * (k >> 3)) & 31;
    *(floatx4*)(tilebuf + (size_t)s * 4) =
        *(const floatx4*)(Wsrc + (size_t)k * 1024 + cc * 4);
  }
#endif
}

// Read B-frag (8 bf16: k = quad*8+j, fixed col) from swizzled fp32 tile.
__device__ inline bf16x8 read_bfrag(const float* __restrict__ tile, int col, int quad) {
  const int cc = col >> 2, c3 = col & 3;
  const int p  = (cc + 4 * quad) & 31;
  const float* base = tile + (size_t)p * 4 + c3 + (size_t)(quad * 8) * 128;
  float f[8];
  #pragma unroll
  for (int j = 0; j < 8; ++j) f[j] = base[(size_t)j * 128];
  union { bf16x8 v; unsigned u[4]; } r;
  #pragma unroll
  for (int j = 0; j < 4; ++j) r.u[j] = pk2(f[2 * j], f[2 * j + 1]);
  return r.v;
}

template<int K, bool A_F32, bool SWISH, bool OUT_BF16>
__global__ __launch_bounds__(256) void gemm_kernel(
    const void* __restrict__ Aall, int lda,
    const float* __restrict__ Wall,   // (16, K, 1024)
    const float* __restrict__ bias,   // (16, 1024)
    const int* __restrict__ cat_ids,
    void* __restrict__ Out, int ldo)
{
  constexpr int N  = 1024;
  constexpr int KT = K / 32;
  __shared__ float wtile[2][32 * 128];     // 2 x 16 KiB
  __shared__ int s_b[80], s_c[80], s_np;

  const int tid = threadIdx.x;
  if (tid < 80) { s_b[tid] = -1; s_c[tid] = 0; }
  __syncthreads();
  if (tid < 64) {                          // wave 0: padded counting sort
    const int myc = cat_ids[tid];
    int rank = 0, pst = 0, tot = 0;
    #pragma unroll
    for (int c = 0; c < 16; ++c) {
      unsigned long long m = __ballot(myc == c);
      const int cnt = __popcll(m);
      const int pc  = 2 * ((cnt + 1) >> 1);  // pad to even
      if (c < myc)  pst += pc;
      if (c == myc) rank = __popcll(m & ((1ull << tid) - 1ull));
      tot += pc;
    }
    const int slot = pst + rank;
    s_b[slot] = tid;
    s_c[slot] = myc;
    if (tid == 0) s_np = tot >> 1;
  }
  __syncthreads();

  const int e = blockIdx.y;
  if (e >= s_np) return;                   // inactive pair slot
  const int b0v = s_b[2 * e];
  int b1 = s_b[2 * e + 1];
  const int c = s_c[2 * e];
  const bool st1 = (b1 >= 0);
  if (!st1) b1 = b0v;                      // dummy: duplicate, mask store

  const int wave = tid >> 6, lane = tid & 63;
  const int quad = lane >> 4, l16 = lane & 15;
  const int wm = wave >> 1, wn = wave & 1; // 2x2 wave grid: M64 x N64 each
  const int ns = blockIdx.x * 128;
  const float* Wc = Wall + (size_t)c * K * N + ns;

  const char* arow[4];
  #pragma unroll
  for (int mt = 0; mt < 4; ++mt) {
    const int pr = wm * 64 + mt * 16 + l16;        // 0..127
    const int batch = (pr < 64) ? b0v : b1;
    const int row = batch * 64 + (pr & 63);
    arow[mt] = (const char*)Aall + (size_t)row * lda * (A_F32 ? 4 : 2);
  }

  floatx4 acc[4][4];
  #pragma unroll
  for (int mt = 0; mt < 4; ++mt)
    #pragma unroll
    for (int nt = 0; nt < 4; ++nt)
      acc[mt][nt] = (floatx4){0.f, 0.f, 0.f, 0.f};

  stage_tile(&wtile[0][0], Wc, tid);
  int buf = 0;
  for (int kt = 0; kt < KT; ++kt) {
    __syncthreads();                       // vmcnt(0) drain -> wtile[buf] ready
    if (kt + 1 < KT)
      stage_tile(&wtile[buf ^ 1][0], Wc + (size_t)(kt + 1) * 32 * 1024, tid);

    const float* tp = &wtile[buf][0];
    const int kk = kt * 32 + quad * 8;

    bf16x8 af[4];
    #pragma unroll
    for (int mt = 0; mt < 4; ++mt) {
      if constexpr (A_F32) {
        const floatx4* p = (const floatx4*)(arow[mt] + (size_t)kk * 4);
        floatx4 x0 = p[0], x1 = p[1];
        union { bf16x8 v; unsigned u[4]; } t;
        t.u[0] = pk2(x0[0], x0[1]); t.u[1] = pk2(x0[2], x0[3]);
        t.u[2] = pk2(x1[0], x1[1]); t.u[3] = pk2(x1[2], x1[3]);
        af[mt] = t.v;
      } else {
        af[mt] = *(const bf16x8*)(arow[mt] + (size_t)kk * 2);
      }
    }

    #pragma unroll
    for (int nt = 0; nt < 4; ++nt) {
      bf16x8 bf = read_bfrag(tp, wn * 64 + nt * 16 + l16, quad);
      #pragma unroll
      for (int mt = 0; mt < 4; ++mt)
        acc[mt][nt] = __builtin_amdgcn_mfma_f32_16x16x32_bf16(af[mt], bf, acc[mt][nt], 0, 0, 0);
    }
    buf ^= 1;
  }

  // Epilogue. C/D: row = quad*4 + r, col = l16 (within 16x16 tile).
  #pragma unroll
  for (int nt = 0; nt < 4; ++nt) {
    const int col = ns + wn * 64 + nt * 16 + l16;
    const float bv = bias[(size_t)c * N + col];
    #pragma unroll
    for (int mt = 0; mt < 4; ++mt) {
      const int prb = wm * 64 + mt * 16 + quad * 4;
      const int batch = (prb < 64) ? b0v : b1;
      const bool do_store = (prb < 64) || st1;
      #pragma unroll
      for (int r = 0; r < 4; ++r) {
        const int row = batch * 64 + ((prb + r) & 63);
        float v = acc[mt][nt][r] + bv;
        if constexpr (SWISH) v = v / (1.f + __expf(-v));
        if (do_store) {
          if constexpr (OUT_BF16)
            ((short*)Out)[(size_t)row * ldo + col] = f2bf(v);
          else
            ((float*)Out)[(size_t)row * ldo + col] = v;
        }
      }
    }
  }
}

// tau: per batch one 1024-vector (timestep constant across T) broadcast to the
// right half of x (row stride 2048 bf16).
__global__ __launch_bounds__(256) void tau_kernel(const int* __restrict__ ts,
                                                  short* __restrict__ x)
{
  const int b = blockIdx.x;
  const float t = (float)ts[b];
  const int tid = threadIdx.x;
  #pragma unroll
  for (int q = 0; q < 4; ++q) {
    const int i  = q * 256 + tid;
    const int hi = i & 511;
    const float e = __expf(-(float)hi * 0.017988946039015980f);  // ln(1e4)/512
    const float freq = t * e;
    const float v = (i < 512) ? sinf(freq) : cosf(freq);
    const short sv = f2bf(v);
    short* base = x + (size_t)(b * 64) * 2048 + 1024 + i;
    #pragma unroll 4
    for (int tt = 0; tt < 64; ++tt) base[(size_t)tt * 2048] = sv;
  }
}

extern "C" void kernel_launch(void* const* d_in, const int* in_sizes, int n_in,
                              void* d_out, int out_size, void* d_ws, size_t ws_size,
                              hipStream_t stream) {
  const float* actions   = (const float*)d_in[0];
  const int*   timesteps = (const int*)  d_in[1];
  const int*   cat_ids   = (const int*)  d_in[2];
  const float* W1 = (const float*)d_in[3];
  const float* b1 = (const float*)d_in[4];
  const float* W2 = (const float*)d_in[5];
  const float* b2 = (const float*)d_in[6];
  const float* W3 = (const float*)d_in[7];
  const float* b3 = (const float*)d_in[8];

  short* x = (short*)d_ws;                     // (4096, 2048) bf16 = 16 MiB
  short* h = x + (size_t)64 * 64 * 2048;       // (4096, 1024) bf16 =  8 MiB

  dim3 grid(8, 40), blk(256);

  gemm_kernel<64, true, false, true><<<grid, blk, 0, stream>>>(
      (const void*)actions, 64, W1, b1, cat_ids, (void*)x, 2048);

  tau_kernel<<<64, 256, 0, stream>>>(timesteps, x);

  gemm_kernel<2048, false, true, true><<<grid, blk, 0, stream>>>(
      (const void*)x, 2048, W2, b2, cat_ids, (void*)h, 1024);

  gemm_kernel<1024, false, false, false><<<grid, blk, 0, stream>>>(
      (const void*)h, 1024, W3, b3, cat_ids, d_out, 1024);
}